// Round 5
// baseline (645.564 us; speedup 1.0000x reference)
//
#include <hip/hip_runtime.h>
#include <cstdint>
#include <cstddef>

#define S_TOK 8192
#define MDIM  2048
#define NE    64
#define CAP   128

typedef float f32x4 __attribute__((ext_vector_type(4)));

// d_out float layout: [0]=l_aux | [1..+67108864)=combine | [..+67108864)=dispatch | [..+64)=exp_counts
static const size_t COMBINE_OFF  = 1;
static const size_t DISPATCH_OFF = 1 + 67108864ULL;
static const size_t COUNTS_OFF   = 1 + 2ULL * 67108864ULL;   // = 134217729

// ---------------------------------------------------------------- transpose wg[e][k] -> wgT[k][e]
__global__ __launch_bounds__(256) void k_transpose(const float* __restrict__ wg,
                                                   float* __restrict__ wgT,
                                                   float* __restrict__ colsum) {
    __shared__ float tile[64][65];
    int t = threadIdx.x, b = blockIdx.x;          // b: k-tile 0..31
    if (b == 0 && t < 64) colsum[t] = 0.f;
    int kq = t & 15, eh = t >> 4;
    #pragma unroll
    for (int p = 0; p < 4; ++p) {
        int e = p * 16 + eh;
        float4 v = *(const float4*)(wg + (size_t)e * MDIM + b * 64 + kq * 4);
        tile[e][kq * 4 + 0] = v.x;
        tile[e][kq * 4 + 1] = v.y;
        tile[e][kq * 4 + 2] = v.z;
        tile[e][kq * 4 + 3] = v.w;
    }
    __syncthreads();
    int eq = t & 15, kh = t >> 4;
    #pragma unroll
    for (int p = 0; p < 4; ++p) {
        int k = p * 16 + kh;
        float4 w;
        w.x = tile[eq * 4 + 0][k];
        w.y = tile[eq * 4 + 1][k];
        w.z = tile[eq * 4 + 2][k];
        w.w = tile[eq * 4 + 3][k];
        *(float4*)(wgT + (size_t)(b * 64 + k) * NE + eq * 4) = w;
    }
}

// ---------------------------------------------------------------- logits GEMM (split-K=4) + fused zero-fill
// grid (128 row-tiles, 4 k-quarters) = 512 blocks, block 256. Tile 64r x 64e, thread 4r x 4e.
// Zero-stores are issued AFTER the staging barrier so they drain while the FMA loop runs;
// the end-of-chunk barrier picks up the remainder. Store pipe stays busy the whole kernel.
#define RT 64
#define KC 32
__global__ __launch_bounds__(256) void k_gemm(const float* __restrict__ in,
                                              const float* __restrict__ wgT,
                                              float* __restrict__ part,
                                              f32x4* __restrict__ zout) {
    __shared__ float in_lds[KC][RT + 4];
    __shared__ float wg_lds[KC][NE];
    int t  = threadIdx.x;
    int r0 = blockIdx.x * RT;
    int kbase = blockIdx.y * (MDIM / 4);
    int bid = blockIdx.y * 128 + blockIdx.x;
    long gtid = (long)bid * 256 + t;               // 0..131071
    int te = t & 15, tr = t >> 4;
    int lk4 = (t & 7) * 4;
    int lr  = t >> 3;
    const f32x4 z4 = {0.f, 0.f, 0.f, 0.f};
    float acc[4][4] = {};
    for (int c = 0; c < 16; ++c) {
        int k0 = kbase + c * KC;
        float4 v0 = *(const float4*)(in + (size_t)(r0 + lr) * MDIM + k0 + lk4);
        float4 v1 = *(const float4*)(in + (size_t)(r0 + lr + 32) * MDIM + k0 + lk4);
        in_lds[lk4 + 0][lr] = v0.x; in_lds[lk4 + 1][lr] = v0.y;
        in_lds[lk4 + 2][lr] = v0.z; in_lds[lk4 + 3][lr] = v0.w;
        in_lds[lk4 + 0][lr + 32] = v1.x; in_lds[lk4 + 1][lr + 32] = v1.y;
        in_lds[lk4 + 2][lr + 32] = v1.z; in_lds[lk4 + 3][lr + 32] = v1.w;
        const float4* src = (const float4*)(wgT + (size_t)k0 * NE);
        float4* dst = (float4*)&wg_lds[0][0];
        dst[t]       = src[t];
        dst[t + 256] = src[t + 256];
        __syncthreads();
        // fused zero-fill: issue 16 nontemporal float4 stores NOW, overlap with FMA below
        #pragma unroll
        for (int j = 0; j < 16; ++j) {
            long idx = ((long)(c * 16 + j) << 17) + gtid;     // stride 131072 float4s
            __builtin_nontemporal_store(z4, zout + idx);
        }
        #pragma unroll
        for (int kk = 0; kk < KC; ++kk) {
            float4 a4 = *(const float4*)&in_lds[kk][tr * 4];
            float4 b4 = *(const float4*)&wg_lds[kk][te * 4];
            float a[4] = {a4.x, a4.y, a4.z, a4.w};
            float b[4] = {b4.x, b4.y, b4.z, b4.w};
            #pragma unroll
            for (int i = 0; i < 4; ++i)
                #pragma unroll
                for (int j = 0; j < 4; ++j)
                    acc[i][j] += a[i] * b[j];
        }
        __syncthreads();
    }
    // tail: float4s [33554432, 33554448) -> covers floats up to 134217792
    if (gtid < 16) __builtin_nontemporal_store(z4, zout + 33554432 + gtid);
    #pragma unroll
    for (int i = 0; i < 4; ++i) {
        size_t base = ((size_t)blockIdx.y * S_TOK + r0 + tr * 4 + i) * NE + te * 4;
        *(float4*)(part + base) = make_float4(acc[i][0], acc[i][1], acc[i][2], acc[i][3]);
    }
}

// ---------------------------------------------------------------- softmax + argmax (lane = expert)
__global__ __launch_bounds__(256) void k_softmax(const float* __restrict__ part,
                                                 float* __restrict__ colsum,
                                                 float* __restrict__ gate_sel,
                                                 int* __restrict__ eid) {
    __shared__ float ls[NE];
    int t = threadIdx.x;
    int lane = t & 63, w = t >> 6;
    if (t < NE) ls[t] = 0.f;
    __syncthreads();
    float lsum = 0.f;
    for (int i = 0; i < 8; ++i) {
        int r = blockIdx.x * 32 + w * 8 + i;
        float v = part[(size_t)r * NE + lane]
                + part[(size_t)(S_TOK + r) * NE + lane]
                + part[(size_t)(2 * S_TOK + r) * NE + lane]
                + part[(size_t)(3 * S_TOK + r) * NE + lane];
        float m = v; int mi = lane;
        for (int off = 32; off > 0; off >>= 1) {
            float om = __shfl_xor(m, off);
            int   oi = __shfl_xor(mi, off);
            if (om > m || (om == m && oi < mi)) { m = om; mi = oi; }
        }
        float ex = expf(v - m);
        float s = ex;
        for (int off = 32; off > 0; off >>= 1) s += __shfl_xor(s, off);
        float gate = ex / s;
        lsum += gate;
        if (lane == mi) { gate_sel[r] = gate; eid[r] = mi; }
    }
    atomicAdd(&ls[lane], lsum);
    __syncthreads();
    if (t < NE) atomicAdd(&colsum[t], ls[t]);
}

// ---------------------------------------------------------------- ranks + scatter + counts + l_aux
__global__ __launch_bounds__(256) void k_ranks_scatter(const int* __restrict__ eid,
                                                       const float* __restrict__ gate_sel,
                                                       const float* __restrict__ colsum,
                                                       float* __restrict__ out) {
    __shared__ int wsum[4];
    int e = blockIdx.x;
    int t = threadIdx.x;
    int lane = t & 63, w = t >> 6;
    int base = 0;
    for (int it = 0; it < S_TOK / 256; ++it) {
        int s = it * 256 + t;
        int m = (eid[s] == e) ? 1 : 0;
        unsigned long long b = __ballot(m);
        int pre = __popcll(b & ((1ull << lane) - 1ull));
        if (lane == 0) wsum[w] = __popcll(b);
        __syncthreads();
        int woff = 0;
        #pragma unroll
        for (int j = 0; j < 4; ++j) if (j < w) woff += wsum[j];
        int tot = wsum[0] + wsum[1] + wsum[2] + wsum[3];
        if (m) {
            int rk = base + woff + pre;
            if (rk < CAP) {
                size_t idx = ((size_t)s * NE + e) * CAP + rk;
                out[COMBINE_OFF + idx]  = gate_sel[s];
                out[DISPATCH_OFF + idx] = 1.0f;
            }
        }
        base += tot;
        __syncthreads();
    }
    if (t == 0) {
        out[COUNTS_OFF + e] = (float)base;
        float term = (colsum[e] / 8192.f) * ((float)base / 8192.f) * 64.f;
        atomicAdd(out, term);
    }
}

extern "C" void kernel_launch(void* const* d_in, const int* in_sizes, int n_in,
                              void* d_out, int out_size, void* d_ws, size_t ws_size,
                              hipStream_t stream) {
    const float* in = (const float*)d_in[0];
    const float* wg = (const float*)d_in[1];
    float* out = (float*)d_out;

    float* colsum   = (float*)d_ws;              // 64 f
    float* gate_sel = colsum + 64;               // 8192 f
    int*   eid      = (int*)(gate_sel + 8192);   // 8192 i
    float* wgT      = (float*)(eid + 8192);      // 131072 f
    float* part     = wgT + 131072;              // 4*8192*64 f

    k_transpose<<<32, 256, 0, stream>>>(wg, wgT, colsum);
    k_gemm<<<dim3(128, 4), 256, 0, stream>>>(in, wgT, part, (f32x4*)out);   // also zeroes d_out
    k_softmax<<<256, 256, 0, stream>>>(part, colsum, gate_sel, eid);
    k_ranks_scatter<<<64, 256, 0, stream>>>(eid, gate_sel, colsum, out);    // counts + l_aux + nonzeros
}

// Round 6
// 626.466 us; speedup vs baseline: 1.0305x; 1.0305x over previous
//
#include <hip/hip_runtime.h>
#include <cstdint>
#include <cstddef>

#define S_TOK 8192
#define MDIM  2048
#define NE    64
#define CAP   128

typedef float f32x4 __attribute__((ext_vector_type(4)));

// d_out float layout: [0]=l_aux | [1..+67108864)=combine | [..+67108864)=dispatch | [..+64)=exp_counts
static const size_t COMBINE_OFF  = 1;
static const size_t DISPATCH_OFF = 1 + 67108864ULL;
static const size_t COUNTS_OFF   = 1 + 2ULL * 67108864ULL;   // = 134217729

// ---------------------------------------------------------------- logits GEMM (split-K=4) + fused
// wg-transpose (in-LDS) + zero-fill of d_out. grid (128 row-tiles, 4 k-quarters) = 512 blocks.
// Tile 64r x 64e, thread 4r x 4e. Zero-stores issued pre-barrier (round-4 ordering: measured best;
// cross-block co-scheduling keeps the store pipe saturated during FMA phases).
#define RT 64
#define KC 32
__global__ __launch_bounds__(256) void k_gemm(const float* __restrict__ in,
                                              const float* __restrict__ wg,
                                              float* __restrict__ part,
                                              f32x4* __restrict__ zout,
                                              float* __restrict__ colsum) {
    __shared__ float in_lds[KC][RT + 4];   // stride 68: 16B-aligned rows, bounded bank aliasing
    __shared__ float wg_lds[KC][NE + 4];
    int t  = threadIdx.x;
    int r0 = blockIdx.x * RT;
    int kbase = blockIdx.y * (MDIM / 4);
    int bid = blockIdx.y * 128 + blockIdx.x;
    long gtid = (long)bid * 256 + t;               // 0..131071
    if (bid == 0 && t < 64) colsum[t] = 0.f;       // zero accumulator for softmax colsum
    int te = t & 15, tr = t >> 4;                  // e0 = te*4, rows = tr*4..tr*4+3
    int kq  = t & 7;                               // float4 group along k
    int row = t >> 3;                              // 0..31 (+32 second half)
    const f32x4 z4 = {0.f, 0.f, 0.f, 0.f};
    float acc[4][4] = {};
    for (int c = 0; c < 16; ++c) {
        int k0 = kbase + c * KC;
        float4 v0 = *(const float4*)(in + (size_t)(r0 + row) * MDIM + k0 + kq * 4);
        float4 v1 = *(const float4*)(in + (size_t)(r0 + row + 32) * MDIM + k0 + kq * 4);
        float4 w0 = *(const float4*)(wg + (size_t)row * MDIM + k0 + kq * 4);
        float4 w1 = *(const float4*)(wg + (size_t)(row + 32) * MDIM + k0 + kq * 4);
        in_lds[kq * 4 + 0][row] = v0.x; in_lds[kq * 4 + 1][row] = v0.y;
        in_lds[kq * 4 + 2][row] = v0.z; in_lds[kq * 4 + 3][row] = v0.w;
        in_lds[kq * 4 + 0][row + 32] = v1.x; in_lds[kq * 4 + 1][row + 32] = v1.y;
        in_lds[kq * 4 + 2][row + 32] = v1.z; in_lds[kq * 4 + 3][row + 32] = v1.w;
        wg_lds[kq * 4 + 0][row] = w0.x; wg_lds[kq * 4 + 1][row] = w0.y;
        wg_lds[kq * 4 + 2][row] = w0.z; wg_lds[kq * 4 + 3][row] = w0.w;
        wg_lds[kq * 4 + 0][row + 32] = w1.x; wg_lds[kq * 4 + 1][row + 32] = w1.y;
        wg_lds[kq * 4 + 2][row + 32] = w1.z; wg_lds[kq * 4 + 3][row + 32] = w1.w;
        // fused zero-fill: 16 nontemporal float4 stores, drain overlaps via cross-block scheduling
        #pragma unroll
        for (int j = 0; j < 16; ++j) {
            long idx = ((long)(c * 16 + j) << 17) + gtid;     // stride 131072 float4s
            __builtin_nontemporal_store(z4, zout + idx);
        }
        __syncthreads();
        #pragma unroll
        for (int kk = 0; kk < KC; ++kk) {
            float4 a4 = *(const float4*)&in_lds[kk][tr * 4];
            float4 b4 = *(const float4*)&wg_lds[kk][te * 4];
            float a[4] = {a4.x, a4.y, a4.z, a4.w};
            float b[4] = {b4.x, b4.y, b4.z, b4.w};
            #pragma unroll
            for (int i = 0; i < 4; ++i)
                #pragma unroll
                for (int j = 0; j < 4; ++j)
                    acc[i][j] += a[i] * b[j];
        }
        __syncthreads();
    }
    // tail: float4s [33554432, 33554448) -> covers floats up to 134217792
    if (gtid < 16) __builtin_nontemporal_store(z4, zout + 33554432 + gtid);
    #pragma unroll
    for (int i = 0; i < 4; ++i) {
        size_t base = ((size_t)blockIdx.y * S_TOK + r0 + tr * 4 + i) * NE + te * 4;
        *(float4*)(part + base) = make_float4(acc[i][0], acc[i][1], acc[i][2], acc[i][3]);
    }
}

// ---------------------------------------------------------------- softmax + argmax (lane = expert)
__global__ __launch_bounds__(256) void k_softmax(const float* __restrict__ part,
                                                 float* __restrict__ colsum,
                                                 float* __restrict__ gate_sel,
                                                 int* __restrict__ eid) {
    __shared__ float ls[NE];
    int t = threadIdx.x;
    int lane = t & 63, w = t >> 6;
    if (t < NE) ls[t] = 0.f;
    __syncthreads();
    float lsum = 0.f;
    for (int i = 0; i < 8; ++i) {
        int r = blockIdx.x * 32 + w * 8 + i;
        float v = part[(size_t)r * NE + lane]
                + part[(size_t)(S_TOK + r) * NE + lane]
                + part[(size_t)(2 * S_TOK + r) * NE + lane]
                + part[(size_t)(3 * S_TOK + r) * NE + lane];
        float m = v; int mi = lane;
        for (int off = 32; off > 0; off >>= 1) {
            float om = __shfl_xor(m, off);
            int   oi = __shfl_xor(mi, off);
            if (om > m || (om == m && oi < mi)) { m = om; mi = oi; }
        }
        float ex = expf(v - m);
        float s = ex;
        for (int off = 32; off > 0; off >>= 1) s += __shfl_xor(s, off);
        float gate = ex / s;
        lsum += gate;
        if (lane == mi) { gate_sel[r] = gate; eid[r] = mi; }
    }
    atomicAdd(&ls[lane], lsum);
    __syncthreads();
    if (t < NE) atomicAdd(&colsum[t], ls[t]);
}

// ---------------------------------------------------------------- ranks + scatter + counts + l_aux
__global__ __launch_bounds__(256) void k_ranks_scatter(const int* __restrict__ eid,
                                                       const float* __restrict__ gate_sel,
                                                       const float* __restrict__ colsum,
                                                       float* __restrict__ out) {
    __shared__ int wsum[4];
    int e = blockIdx.x;
    int t = threadIdx.x;
    int lane = t & 63, w = t >> 6;
    int base = 0;
    for (int it = 0; it < S_TOK / 256; ++it) {
        int s = it * 256 + t;
        int m = (eid[s] == e) ? 1 : 0;
        unsigned long long b = __ballot(m);
        int pre = __popcll(b & ((1ull << lane) - 1ull));
        if (lane == 0) wsum[w] = __popcll(b);
        __syncthreads();
        int woff = 0;
        #pragma unroll
        for (int j = 0; j < 4; ++j) if (j < w) woff += wsum[j];
        int tot = wsum[0] + wsum[1] + wsum[2] + wsum[3];
        if (m) {
            int rk = base + woff + pre;
            if (rk < CAP) {
                size_t idx = ((size_t)s * NE + e) * CAP + rk;
                out[COMBINE_OFF + idx]  = gate_sel[s];
                out[DISPATCH_OFF + idx] = 1.0f;
            }
        }
        base += tot;
        __syncthreads();
    }
    if (t == 0) {
        out[COUNTS_OFF + e] = (float)base;
        float term = (colsum[e] / 8192.f) * ((float)base / 8192.f) * 64.f;
        atomicAdd(out, term);
    }
}

extern "C" void kernel_launch(void* const* d_in, const int* in_sizes, int n_in,
                              void* d_out, int out_size, void* d_ws, size_t ws_size,
                              hipStream_t stream) {
    const float* in = (const float*)d_in[0];
    const float* wg = (const float*)d_in[1];
    float* out = (float*)d_out;

    float* colsum   = (float*)d_ws;              // 64 f
    float* gate_sel = colsum + 64;               // 8192 f
    int*   eid      = (int*)(gate_sel + 8192);   // 8192 i
    float* part     = (float*)(eid + 8192);      // 4*8192*64 f

    k_gemm<<<dim3(128, 4), 256, 0, stream>>>(in, wg, part, (f32x4*)out, colsum);  // zero+transpose fused
    k_softmax<<<256, 256, 0, stream>>>(part, colsum, gate_sel, eid);
    k_ranks_scatter<<<64, 256, 0, stream>>>(eid, gate_sel, colsum, out);          // counts + l_aux + nonzeros
}

// Round 7
// 614.284 us; speedup vs baseline: 1.0509x; 1.0198x over previous
//
#include <hip/hip_runtime.h>
#include <cstdint>
#include <cstddef>

#define S_TOK 8192
#define MDIM  2048
#define NE    64
#define CAP   128
#define NSEG  256   // 32-token segments

typedef float f32x4 __attribute__((ext_vector_type(4)));

// d_out float layout: [0]=l_aux | [1..+67108864)=combine | [..+67108864)=dispatch | [..+64)=exp_counts
static const size_t COMBINE_OFF  = 1;
static const size_t DISPATCH_OFF = 1 + 67108864ULL;
static const size_t COUNTS_OFF   = 1 + 2ULL * 67108864ULL;   // = 134217729

// ---------------------------------------------------------------- logits GEMM (split-K=4) + fused
// wg-transpose (in-LDS) + zero-fill of d_out. grid (128 row-tiles, 4 k-quarters) = 512 blocks.
// Tile 64r x 64e, thread 4r x 4e. Zero-stores pre-barrier (measured best: cross-block
// co-scheduling keeps the store pipe saturated during FMA phases).
#define RT 64
#define KC 32
__global__ __launch_bounds__(256) void k_gemm(const float* __restrict__ in,
                                              const float* __restrict__ wg,
                                              float* __restrict__ part,
                                              f32x4* __restrict__ zout,
                                              float* __restrict__ colsum) {
    __shared__ float in_lds[KC][RT + 4];
    __shared__ float wg_lds[KC][NE + 4];
    int t  = threadIdx.x;
    int r0 = blockIdx.x * RT;
    int kbase = blockIdx.y * (MDIM / 4);
    int bid = blockIdx.y * 128 + blockIdx.x;
    long gtid = (long)bid * 256 + t;               // 0..131071
    if (bid == 0 && t < 64) colsum[t] = 0.f;
    int te = t & 15, tr = t >> 4;
    int kq  = t & 7;
    int row = t >> 3;
    const f32x4 z4 = {0.f, 0.f, 0.f, 0.f};
    float acc[4][4] = {};
    for (int c = 0; c < 16; ++c) {
        int k0 = kbase + c * KC;
        float4 v0 = *(const float4*)(in + (size_t)(r0 + row) * MDIM + k0 + kq * 4);
        float4 v1 = *(const float4*)(in + (size_t)(r0 + row + 32) * MDIM + k0 + kq * 4);
        float4 w0 = *(const float4*)(wg + (size_t)row * MDIM + k0 + kq * 4);
        float4 w1 = *(const float4*)(wg + (size_t)(row + 32) * MDIM + k0 + kq * 4);
        in_lds[kq * 4 + 0][row] = v0.x; in_lds[kq * 4 + 1][row] = v0.y;
        in_lds[kq * 4 + 2][row] = v0.z; in_lds[kq * 4 + 3][row] = v0.w;
        in_lds[kq * 4 + 0][row + 32] = v1.x; in_lds[kq * 4 + 1][row + 32] = v1.y;
        in_lds[kq * 4 + 2][row + 32] = v1.z; in_lds[kq * 4 + 3][row + 32] = v1.w;
        wg_lds[kq * 4 + 0][row] = w0.x; wg_lds[kq * 4 + 1][row] = w0.y;
        wg_lds[kq * 4 + 2][row] = w0.z; wg_lds[kq * 4 + 3][row] = w0.w;
        wg_lds[kq * 4 + 0][row + 32] = w1.x; wg_lds[kq * 4 + 1][row + 32] = w1.y;
        wg_lds[kq * 4 + 2][row + 32] = w1.z; wg_lds[kq * 4 + 3][row + 32] = w1.w;
        #pragma unroll
        for (int j = 0; j < 16; ++j) {
            long idx = ((long)(c * 16 + j) << 17) + gtid;     // stride 131072 float4s
            __builtin_nontemporal_store(z4, zout + idx);
        }
        __syncthreads();
        #pragma unroll
        for (int kk = 0; kk < KC; ++kk) {
            float4 a4 = *(const float4*)&in_lds[kk][tr * 4];
            float4 b4 = *(const float4*)&wg_lds[kk][te * 4];
            float a[4] = {a4.x, a4.y, a4.z, a4.w};
            float b[4] = {b4.x, b4.y, b4.z, b4.w};
            #pragma unroll
            for (int i = 0; i < 4; ++i)
                #pragma unroll
                for (int j = 0; j < 4; ++j)
                    acc[i][j] += a[i] * b[j];
        }
        __syncthreads();
    }
    if (gtid < 16) __builtin_nontemporal_store(z4, zout + 33554432 + gtid);
    #pragma unroll
    for (int i = 0; i < 4; ++i) {
        size_t base = ((size_t)blockIdx.y * S_TOK + r0 + tr * 4 + i) * NE + te * 4;
        *(float4*)(part + base) = make_float4(acc[i][0], acc[i][1], acc[i][2], acc[i][3]);
    }
}

// ---------------------------------------------------------------- softmax + argmax + seg histogram
// 256 blocks x 32 rows. Also emits segcnt[e][seg] = hits for expert e in this 32-row segment.
__global__ __launch_bounds__(256) void k_softmax(const float* __restrict__ part,
                                                 float* __restrict__ colsum,
                                                 float* __restrict__ gate_sel,
                                                 int* __restrict__ eid,
                                                 int* __restrict__ segcnt) {
    __shared__ float ls[NE];
    __shared__ int hist[NE];
    int t = threadIdx.x;
    int lane = t & 63, w = t >> 6;
    if (t < NE) { ls[t] = 0.f; hist[t] = 0; }
    __syncthreads();
    float lsum = 0.f;
    for (int i = 0; i < 8; ++i) {
        int r = blockIdx.x * 32 + w * 8 + i;
        float v = part[(size_t)r * NE + lane]
                + part[(size_t)(S_TOK + r) * NE + lane]
                + part[(size_t)(2 * S_TOK + r) * NE + lane]
                + part[(size_t)(3 * S_TOK + r) * NE + lane];
        float m = v; int mi = lane;
        for (int off = 32; off > 0; off >>= 1) {
            float om = __shfl_xor(m, off);
            int   oi = __shfl_xor(mi, off);
            if (om > m || (om == m && oi < mi)) { m = om; mi = oi; }
        }
        float ex = expf(v - m);
        float s = ex;
        for (int off = 32; off > 0; off >>= 1) s += __shfl_xor(s, off);
        float gate = ex / s;
        lsum += gate;
        if (lane == mi) { gate_sel[r] = gate; eid[r] = mi; atomicAdd(&hist[mi], 1); }
    }
    atomicAdd(&ls[lane], lsum);
    __syncthreads();
    if (t < NE) {
        atomicAdd(&colsum[t], ls[t]);
        segcnt[t * NSEG + blockIdx.x] = hist[t];   // [e][seg]
    }
}

// ---------------------------------------------------------------- ranks + scatter + counts + l_aux
// Block e: exclusive scan of 256 segment counts (1 barrier), then thread t walks its
// 32-token segment with a running rank. Threads whose base rank >= CAP exit immediately.
__global__ __launch_bounds__(256) void k_ranks_scatter(const int* __restrict__ eid,
                                                       const float* __restrict__ gate_sel,
                                                       const int* __restrict__ segcnt,
                                                       const float* __restrict__ colsum,
                                                       float* __restrict__ out) {
    __shared__ int wsum[4];
    int e = blockIdx.x;
    int t = threadIdx.x;
    int lane = t & 63, w = t >> 6;
    int c = segcnt[e * NSEG + t];
    // inclusive wave scan
    int incl = c;
    #pragma unroll
    for (int off = 1; off < 64; off <<= 1) {
        int v = __shfl_up(incl, off);
        if (lane >= off) incl += v;
    }
    if (lane == 63) wsum[w] = incl;
    __syncthreads();
    int woff = 0;
    #pragma unroll
    for (int j = 0; j < 4; ++j) if (j < w) woff += wsum[j];
    int excl = woff + incl - c;                    // tokens for e before this segment
    if (t == 0) {
        int total = wsum[0] + wsum[1] + wsum[2] + wsum[3];
        out[COUNTS_OFF + e] = (float)total;
        float term = (colsum[e] / 8192.f) * ((float)total / 8192.f) * 64.f;
        atomicAdd(out, term);                      // l_aux (out[0] zeroed by k_gemm)
    }
    if (c == 0 || excl >= CAP) return;             // nothing to write from this segment
    int run = excl;
    int base_s = t * 32;
    #pragma unroll 4
    for (int j = 0; j < 32; ++j) {
        if (run >= CAP) break;
        int s = base_s + j;
        if (eid[s] == e) {
            size_t idx = ((size_t)s * NE + e) * CAP + run;
            out[COMBINE_OFF + idx]  = gate_sel[s];
            out[DISPATCH_OFF + idx] = 1.0f;
            ++run;
        }
    }
}

extern "C" void kernel_launch(void* const* d_in, const int* in_sizes, int n_in,
                              void* d_out, int out_size, void* d_ws, size_t ws_size,
                              hipStream_t stream) {
    const float* in = (const float*)d_in[0];
    const float* wg = (const float*)d_in[1];
    float* out = (float*)d_out;

    float* colsum   = (float*)d_ws;              // 64 f
    float* gate_sel = colsum + 64;               // 8192 f
    int*   eid      = (int*)(gate_sel + 8192);   // 8192 i
    int*   segcnt   = eid + 8192;                // 64*256 i
    float* part     = (float*)(segcnt + NE * NSEG);  // 4*8192*64 f

    k_gemm<<<dim3(128, 4), 256, 0, stream>>>(in, wg, part, (f32x4*)out, colsum);
    k_softmax<<<256, 256, 0, stream>>>(part, colsum, gate_sel, eid, segcnt);
    k_ranks_scatter<<<64, 256, 0, stream>>>(eid, gate_sel, segcnt, colsum, out);
}